// Round 6
// baseline (293.420 us; speedup 1.0000x reference)
//
#include <hip/hip_runtime.h>
#include <hip/hip_bf16.h>

#define NB   32
#define SEQ  512
#define HID  768
#define FFN  3072
#define NEXP 8

typedef float f32x4 __attribute__((ext_vector_type(4)));
typedef short s16x8 __attribute__((ext_vector_type(8)));

__device__ __forceinline__ unsigned short f2bf(float f) {
    return __builtin_bit_cast(unsigned short, (__bf16)f);
}

__device__ __forceinline__ float fast_exp2(float x) {
    float r; asm("v_exp_f32 %0, %1" : "=v"(r) : "v"(x)); return r;
}
__device__ __forceinline__ float fast_rcp(float x) {
    float r; asm("v_rcp_f32 %0, %1" : "=v"(r) : "v"(x)); return r;
}

// tanh-gelu, overflow-free (exp2 arg <= 0). |error| vs exact-erf gelu ~2e-4.
__device__ __forceinline__ float gelu_fast(float v) {
    float u  = v * (0.7978845608f + 0.0356774081f * v * v);
    float t  = fast_exp2(-2.8853900817779268f * fabsf(u));   // e^{-2|u|}
    float T  = (1.0f - t) * fast_rcp(1.0f + t);              // tanh(|u|)
    return 0.5f * v + 0.5f * fabsf(v) * T;
}

#define GLOAD16(gp, lp) __builtin_amdgcn_global_load_lds( \
    (const __attribute__((address_space(1))) unsigned int*)(gp), \
    (__attribute__((address_space(3))) unsigned int*)(lp), 16, 0, 0)

// ---------------------------------------------------------------------------
// stable counting-sort permutation of sentences by expert label (1 wave)
// ---------------------------------------------------------------------------
__global__ void sort_labels_kernel(const int* __restrict__ labels, int* __restrict__ perm)
{
    int i = threadIdx.x;
    if (i < NB) {
        int li = labels[i];
        int rank = 0;
        for (int j = 0; j < NB; j++) {
            int lj = labels[j];
            if (lj < li || (lj == li && j < i)) rank++;
        }
        perm[rank] = i;
    }
}

// ---------------------------------------------------------------------------
// convert X fp32 -> bf16
// ---------------------------------------------------------------------------
__global__ __launch_bounds__(256) void cvt_x_kernel(
    const float* __restrict__ X, unsigned short* __restrict__ Xb, int n8)
{
    int idx = blockIdx.x * blockDim.x + threadIdx.x;
    int stride = gridDim.x * blockDim.x;
    for (int i = idx; i < n8; i += stride) {
        f32x4 a = *(const f32x4*)(X + (size_t)i * 8);
        f32x4 b = *(const f32x4*)(X + (size_t)i * 8 + 4);
        unsigned short o[8];
#pragma unroll
        for (int v = 0; v < 4; v++) o[v] = f2bf(a[v]);
#pragma unroll
        for (int v = 0; v < 4; v++) o[4 + v] = f2bf(b[v]);
        *(s16x8*)(Xb + (size_t)i * 8) = *(s16x8*)o;
    }
}

// ---------------------------------------------------------------------------
// convert + transpose: in [R][C] fp32 -> out [C][R] bf16 per slab
// ---------------------------------------------------------------------------
__global__ __launch_bounds__(256) void cvt_transpose_kernel(
    const float* __restrict__ W, unsigned short* __restrict__ WT, int R, int C)
{
    __shared__ unsigned short tile[64][65];
    const int cb = blockIdx.x * 64, rb = blockIdx.y * 64;
    const float* src = W + (size_t)blockIdx.z * R * C;
    unsigned short* dst = WT + (size_t)blockIdx.z * R * C;
    const int x = threadIdx.x & 63, y0 = threadIdx.x >> 6;
#pragma unroll
    for (int i = 0; i < 16; i++) {
        int r = y0 + i * 4;
        tile[r][x] = f2bf(src[(size_t)(rb + r) * C + cb + x]);
    }
    __syncthreads();
#pragma unroll
    for (int i = 0; i < 16; i++) {
        int c = y0 + i * 4;
        dst[(size_t)(cb + c) * R + rb + x] = tile[x][c];
    }
}

// ---------------------------------------------------------------------------
// 256x256 8-phase GEMM (BK=64, 8 waves, 2 LDS buffers of 64KB).
// Window phases (frag-persistent, 24 ds_read_b128/window/wave):
//   wp0 (A0,B0) stage A1(t+1)->nxt | wp1 (A0,B1) stage B1(t+1)->nxt
//   wp2 (A1,B1) stage A0(t+2)->cur | wp3 (A1,B0) stage B0(t+2)->cur + vmcnt(4)
// ---------------------------------------------------------------------------
template<int LDB, bool ISA>
__device__ __forceinline__ void stage_region(const char* g, char* lds, int half, int tid)
{
#pragma unroll
    for (int p = 0; p < 2; p++) {
        int L  = p * 8192 + tid * 16;
        int rr = L >> 7;
        int cb = L & 127;
        int row = ISA ? ((rr & 63) + ((rr >> 6) << 7) + half * 64)
                      : ((rr & 31) + ((rr >> 5) << 6) + half * 32);
        int cbs = cb ^ ((row & 7) << 4);
        GLOAD16(g + (size_t)row * LDB + cbs, lds + (size_t)row * 128 + cb);
    }
}

__device__ __forceinline__ void read_af(const char* Ab, int arow_b, int k0, int ih, s16x8 (&a)[2][4])
{
    const int k1 = k0 ^ 64;
#pragma unroll
    for (int i = 0; i < 4; i++) {
        const char* p = Ab + arow_b + (ih * 64 + i * 16) * 128;
        a[0][i] = *(const s16x8*)(p + k0);
        a[1][i] = *(const s16x8*)(p + k1);
    }
}
__device__ __forceinline__ void read_bf(const char* Bb, int brow_b, int k0, int jh, s16x8 (&b)[2][2])
{
    const int k1 = k0 ^ 64;
#pragma unroll
    for (int j = 0; j < 2; j++) {
        const char* p = Bb + brow_b + (jh * 32 + j * 16) * 128;
        b[0][j] = *(const s16x8*)(p + k0);
        b[1][j] = *(const s16x8*)(p + k1);
    }
}

template<int IH, int JH>
__device__ __forceinline__ void mfma_quad(s16x8 (&a)[2][4], s16x8 (&b)[2][2], f32x4 (&acc)[8][4])
{
    __builtin_amdgcn_s_setprio(1);
#pragma unroll
    for (int kk = 0; kk < 2; kk++)
#pragma unroll
        for (int i = 0; i < 4; i++)
#pragma unroll
            for (int j = 0; j < 2; j++)
                acc[IH * 4 + i][JH * 2 + j] = __builtin_amdgcn_mfma_f32_16x16x32_bf16(
                    a[kk][i], b[kk][j], acc[IH * 4 + i][JH * 2 + j], 0, 0, 0);
    __builtin_amdgcn_s_setprio(0);
}

template<int LDB, bool S1, bool S2, int VM>
__device__ __forceinline__ void gwindow(const char* AgK, const char* BgK,
    char* Acur, char* Bcur, char* Anxt, char* Bnxt,
    int arow_b, int brow_b, int k0, int tid, f32x4 (&acc)[8][4])
{
    s16x8 a[2][4], b0[2][2], b1[2][2];
    // wp0 (A0,B0)
    read_af(Acur, arow_b, k0, 0, a);
    read_bf(Bcur, brow_b, k0, 0, b0);
    if constexpr (S1) stage_region<LDB, true >(AgK + 128, Anxt, 1, tid);
    __builtin_amdgcn_s_barrier();
    mfma_quad<0, 0>(a, b0, acc);
    __builtin_amdgcn_s_barrier();
    // wp1 (A0,B1)
    read_bf(Bcur, brow_b, k0, 1, b1);
    if constexpr (S1) stage_region<LDB, false>(BgK + 128, Bnxt, 1, tid);
    __builtin_amdgcn_s_barrier();
    mfma_quad<0, 1>(a, b1, acc);
    __builtin_amdgcn_s_barrier();
    // wp2 (A1,B1)
    read_af(Acur, arow_b, k0, 1, a);
    if constexpr (S2) stage_region<LDB, true >(AgK + 256, Acur, 0, tid);
    __builtin_amdgcn_s_barrier();
    mfma_quad<1, 1>(a, b1, acc);
    __builtin_amdgcn_s_barrier();
    // wp3 (A1,B0) — all operands already in regs
    if constexpr (S2) stage_region<LDB, false>(BgK + 256, Bcur, 0, tid);
    __builtin_amdgcn_s_barrier();
    mfma_quad<1, 0>(a, b0, acc);
    if constexpr (VM >= 0)
        asm volatile("s_waitcnt vmcnt(%0)" :: "i"(VM) : "memory");
    __builtin_amdgcn_s_barrier();
}

template<int LDB>
__device__ __forceinline__ void gemm_mainloop(const char* Ag, const char* Bg,
    char* smem, int KT, int tid, int arow_b, int brow_b, int k0, f32x4 (&acc)[8][4])
{
    // prologue: A0(0),B0(0),A1(0),B1(0),A0(1),B0(1)
    stage_region<LDB, true >(Ag,       smem,          0, tid);
    stage_region<LDB, false>(Bg,       smem + 65536,  0, tid);
    stage_region<LDB, true >(Ag,       smem,          1, tid);
    stage_region<LDB, false>(Bg,       smem + 65536,  1, tid);
    stage_region<LDB, true >(Ag + 128, smem + 32768,  0, tid);
    stage_region<LDB, false>(Bg + 128, smem + 98304,  0, tid);
    asm volatile("s_waitcnt vmcnt(4)" ::: "memory");
    __builtin_amdgcn_s_barrier();

    int cur = 0;
    for (int kt = 0; kt < KT - 2; ++kt) {
        char* Acur = smem + (cur << 15);
        char* Anxt = smem + ((cur ^ 1) << 15);
        char* Bcur = smem + 65536 + (cur << 15);
        char* Bnxt = smem + 65536 + ((cur ^ 1) << 15);
        gwindow<LDB, true, true, 4>(Ag + (size_t)kt * 128, Bg + (size_t)kt * 128,
            Acur, Bcur, Anxt, Bnxt, arow_b, brow_b, k0, tid, acc);
        cur ^= 1;
    }
    {   // window KT-2: stage A1/B1(KT-1) only; drain
        char* Acur = smem + (cur << 15);
        char* Anxt = smem + ((cur ^ 1) << 15);
        char* Bcur = smem + 65536 + (cur << 15);
        char* Bnxt = smem + 65536 + ((cur ^ 1) << 15);
        gwindow<LDB, true, false, 0>(Ag + (size_t)(KT - 2) * 128, Bg + (size_t)(KT - 2) * 128,
            Acur, Bcur, Anxt, Bnxt, arow_b, brow_b, k0, tid, acc);
        cur ^= 1;
    }
    {   // window KT-1: no stages, no wait
        char* Acur = smem + (cur << 15);
        char* Anxt = smem + ((cur ^ 1) << 15);
        char* Bcur = smem + 65536 + (cur << 15);
        char* Bnxt = smem + 65536 + ((cur ^ 1) << 15);
        gwindow<LDB, false, false, -1>(Ag + (size_t)(KT - 1) * 128, Bg + (size_t)(KT - 1) * 128,
            Acur, Bcur, Anxt, Bnxt, arow_b, brow_b, k0, tid, acc);
    }
}

// ---------------------------------------------------------------------------
// Kernel 1: G = gelu(Xb @ W1[e] + b1[e]) -> bf16
// Round-synchronized XCD mapping: 3 rounds x 256 CUs; per XCD per round:
// 8 (bs,mt) pairs x 4 nt. A panels (3MB/XCD) persist across rounds in L2;
// each B panel multicast by 8 concurrent blocks. G stored non-temporally.
// ---------------------------------------------------------------------------
__global__ __launch_bounds__(512, 2) void moe_gemm1(
    const unsigned short* __restrict__ Xb,
    const int*   __restrict__ labels,
    const int*   __restrict__ perm,
    const unsigned short* __restrict__ W1T,  // [E][FFN][HID]
    const float* __restrict__ B1,
    unsigned short* __restrict__ G)
{
    extern __shared__ char smem[];
    const int L = blockIdx.x;
    const int xcd  = L & 7;
    const int r    = L >> 8;          // dispatch round 0..2
    const int i    = (L >> 3) & 31;   // slot within round on this XCD
    const int pair = i >> 2;          // 0..7
    const int bs = perm[xcd * 4 + (pair >> 1)];
    const int mt = pair & 1;
    const int nt = r * 4 + (i & 3);
    const int e  = labels[bs];

    const char* Ag = (const char*)(Xb + ((size_t)bs * SEQ + (size_t)mt * 256) * HID);
    const char* Bg = (const char*)(W1T + (size_t)e * FFN * HID + (size_t)nt * 256 * HID);

    const int tid = threadIdx.x;
    const int lane = tid & 63, w = tid >> 6;
    const int wm = (w >> 2) * 128, wn = (w & 3) * 64;
    const int fr = lane & 15, fq = lane >> 4;
    const int arow_b = (wm + fr) * 128, brow_b = (wn + fr) * 128;
    const int k0 = (fq * 16) ^ ((fr & 7) << 4);

    f32x4 acc[8][4];
#pragma unroll
    for (int i2 = 0; i2 < 8; i2++)
#pragma unroll
        for (int j = 0; j < 4; j++) acc[i2][j] = (f32x4)0.0f;

    gemm_mainloop<HID * 2>(Ag, Bg, smem, HID / 64, tid, arow_b, brow_b, k0, acc);

    const float* b1g = B1 + (size_t)e * FFN + (size_t)nt * 256;
    unsigned short* Cg = G + ((size_t)bs * SEQ + (size_t)mt * 256) * FFN + (size_t)nt * 256;
    float bias[4];
#pragma unroll
    for (int nj = 0; nj < 4; nj++) bias[nj] = b1g[wn + nj * 16 + fr];
#pragma unroll
    for (int mi = 0; mi < 8; mi++)
#pragma unroll
        for (int nj = 0; nj < 4; nj++) {
            const int col = wn + nj * 16 + fr;
#pragma unroll
            for (int rr2 = 0; rr2 < 4; rr2++) {
                const int row = wm + mi * 16 + fq * 4 + rr2;
                float v = acc[mi][nj][rr2] + bias[nj];
                __builtin_nontemporal_store(f2bf(gelu_fast(v)),
                                            &Cg[(size_t)row * FFN + col]);
            }
        }
}

// ---------------------------------------------------------------------------
// Kernel 2: Out = G @ W2[e] + b2[e] -> fp32 (single dispatch round)
// ---------------------------------------------------------------------------
__global__ __launch_bounds__(512, 2) void moe_gemm2(
    const unsigned short* __restrict__ G,
    const int*   __restrict__ labels,
    const int*   __restrict__ perm,
    const unsigned short* __restrict__ W2T,  // [E][HID][FFN]
    const float* __restrict__ B2,
    float* __restrict__ Out)
{
    extern __shared__ char smem[];
    const int L = blockIdx.x;
    const int xcd = L & 7, s = L >> 3;       // s in [0,24)
    const int bs = perm[xcd * 4 + s / 6];
    const int rr = s % 6;
    const int mt = rr / 3, nt = rr % 3;
    const int e  = labels[bs];

    const char* Ag = (const char*)(G + ((size_t)bs * SEQ + (size_t)mt * 256) * FFN);
    const char* Bg = (const char*)(W2T + (size_t)e * HID * FFN + (size_t)nt * 256 * FFN);

    const int tid = threadIdx.x;
    const int lane = tid & 63, w = tid >> 6;
    const int wm = (w >> 2) * 128, wn = (w & 3) * 64;
    const int fr = lane & 15, fq = lane >> 4;
    const int arow_b = (wm + fr) * 128, brow_b = (wn + fr) * 128;
    const int k0 = (fq * 16) ^ ((fr & 7) << 4);

    f32x4 acc[8][4];
#pragma unroll
    for (int i = 0; i < 8; i++)
#pragma unroll
        for (int j = 0; j < 4; j++) acc[i][j] = (f32x4)0.0f;

    gemm_mainloop<FFN * 2>(Ag, Bg, smem, FFN / 64, tid, arow_b, brow_b, k0, acc);

    const float* b2g = B2 + (size_t)e * HID + (size_t)nt * 256;
    float* Cg = Out + ((size_t)bs * SEQ + (size_t)mt * 256) * HID + (size_t)nt * 256;
    float bias[4];
#pragma unroll
    for (int nj = 0; nj < 4; nj++) bias[nj] = b2g[wn + nj * 16 + fr];
#pragma unroll
    for (int mi = 0; mi < 8; mi++)
#pragma unroll
        for (int nj = 0; nj < 4; nj++) {
            const int col = wn + nj * 16 + fr;
#pragma unroll
            for (int r = 0; r < 4; r++) {
                const int row = wm + mi * 16 + fq * 4 + r;
                __builtin_nontemporal_store(acc[mi][nj][r] + bias[nj],
                                            &Cg[(size_t)row * HID + col]);
            }
        }
}

extern "C" void kernel_launch(void* const* d_in, const int* in_sizes, int n_in,
                              void* d_out, int out_size, void* d_ws, size_t ws_size,
                              hipStream_t stream) {
    const float* X      = (const float*)d_in[0];
    const int*   labels = (const int*)  d_in[1];
    const float* W1     = (const float*)d_in[2];
    const float* B1     = (const float*)d_in[3];
    const float* W2     = (const float*)d_in[4];
    const float* B2     = (const float*)d_in[5];
    float* Out = (float*)d_out;

    char* ws = (char*)d_ws;
    unsigned short* Xb  = (unsigned short*)(ws);               // 25,165,824 B
    unsigned short* W1T = (unsigned short*)(ws + 25165824);    // 37,748,736 B
    unsigned short* W2T = (unsigned short*)(ws + 62914560);    // 37,748,736 B
    unsigned short* G   = (unsigned short*)(ws + 100663296);   // 100,663,296 B
    int*            perm = (int*)(ws + 201326592);             // 128 B

    (void)hipFuncSetAttribute((const void*)moe_gemm1,
        hipFuncAttributeMaxDynamicSharedMemorySize, 131072);
    (void)hipFuncSetAttribute((const void*)moe_gemm2,
        hipFuncAttributeMaxDynamicSharedMemorySize, 131072);

    sort_labels_kernel<<<1, 64, 0, stream>>>(labels, perm);
    cvt_x_kernel<<<2048, 256, 0, stream>>>(X, Xb, NB * SEQ * HID / 8);
    cvt_transpose_kernel<<<dim3(FFN / 64, HID / 64, NEXP), 256, 0, stream>>>(W1, W1T, HID, FFN);
    cvt_transpose_kernel<<<dim3(HID / 64, FFN / 64, NEXP), 256, 0, stream>>>(W2, W2T, FFN, HID);

    moe_gemm1<<<768, dim3(512), 131072, stream>>>(Xb, labels, perm, W1T, B1, G);
    moe_gemm2<<<192, dim3(512), 131072, stream>>>(G, labels, perm, W2T, B2, Out);
}